// Round 5
// baseline (1173.335 us; speedup 1.0000x reference)
//
#include <hip/hip_runtime.h>
#include <float.h>

#define D 512
#define QB 64           // queries per block (N dim of MFMA)
#define PW 64           // points per wave (M dim per wave)
#define PB 256          // points per block-tile (4 waves)
#define NCH 64          // chunks over the point dim (grid.y)
#define MPCL 3          // per-lane candidate list length
#define MPC 8           // candidates kept per (query, chunk)
#define TR 16           // candidates exactly rescored per query

typedef __attribute__((ext_vector_type(8))) short short8;
typedef __attribute__((ext_vector_type(4))) float f32x4;

__device__ __forceinline__ unsigned short f2bf(float f) {
    unsigned u = __float_as_uint(f);
    return (unsigned short)((u + 0x7FFF + ((u >> 16) & 1)) >> 16);
}

template <int K>
__device__ __forceinline__ void insertK(float* bs, int* bi, float v, int id) {
    if (v < bs[K - 1]) {
        bs[K - 1] = v; bi[K - 1] = id;
#pragma unroll
        for (int r = K - 1; r >= 1; --r) {
            if (bs[r] < bs[r - 1]) {
                float tf = bs[r]; bs[r] = bs[r - 1]; bs[r - 1] = tf;
                int ti = bi[r]; bi[r] = bi[r - 1]; bi[r - 1] = ti;
            }
        }
    }
}

// X fp32 -> bf16 (zero-padded rows) + exact fp32 ||x||^2 (1e30 for pad rows).
__global__ void convert_x(const float* __restrict__ X, unsigned short* __restrict__ Xbf,
                          float* __restrict__ xsq, int N, int padN) {
    int row = blockIdx.x * 4 + (threadIdx.x >> 6);
    int lane = threadIdx.x & 63;
    if (row >= padN) return;
    unsigned short ob[8];
    float s = 0.0f;
    if (row < N) {
        const float* p = X + (size_t)row * D + lane * 8;
        float4 a = *(const float4*)p;
        float4 b = *(const float4*)(p + 4);
        s = a.x * a.x + a.y * a.y + a.z * a.z + a.w * a.w
          + b.x * b.x + b.y * b.y + b.z * b.z + b.w * b.w;
        ob[0] = f2bf(a.x); ob[1] = f2bf(a.y); ob[2] = f2bf(a.z); ob[3] = f2bf(a.w);
        ob[4] = f2bf(b.x); ob[5] = f2bf(b.y); ob[6] = f2bf(b.z); ob[7] = f2bf(b.w);
    } else {
#pragma unroll
        for (int i = 0; i < 8; ++i) ob[i] = 0;
    }
    *(uint4*)(Xbf + (size_t)row * D + lane * 8) = *(uint4*)ob;
#pragma unroll
    for (int off = 32; off > 0; off >>= 1) s += __shfl_down(s, off, 64);
    if (lane == 0) xsq[row] = (row < N) ? s : 1e30f;
}

// Q fp32 -> bf16(-2*q).
__global__ void convert_q(const float* __restrict__ Q, unsigned short* __restrict__ Qbf) {
    int row = blockIdx.x * 4 + (threadIdx.x >> 6);
    int lane = threadIdx.x & 63;
    const float* p = Q + (size_t)row * D + lane * 8;
    float4 a = *(const float4*)p;
    float4 b = *(const float4*)(p + 4);
    unsigned short ob[8];
    ob[0] = f2bf(-2.0f * a.x); ob[1] = f2bf(-2.0f * a.y);
    ob[2] = f2bf(-2.0f * a.z); ob[3] = f2bf(-2.0f * a.w);
    ob[4] = f2bf(-2.0f * b.x); ob[5] = f2bf(-2.0f * b.y);
    ob[6] = f2bf(-2.0f * b.z); ob[7] = f2bf(-2.0f * b.w);
    *(uint4*)(Qbf + (size_t)row * D + lane * 8) = *(uint4*)ob;
}

// Transposed MFMA scorer: A = X (points, M), B = Q (queries, N).
// Q (64 x 512 bf16) LDS-resident for the whole kernel (staged once, swizzled);
// X fragments stream global -> VGPR (2-deep pipeline). Selection is per-lane
// in registers (acc col = query). No barriers in the tile loop.
__global__ __launch_bounds__(256, 2) void score_mfma(
    const unsigned short* __restrict__ Qbf,
    const unsigned short* __restrict__ Xbf,
    const float* __restrict__ xsq,
    float* __restrict__ candS, int* __restrict__ candI,
    int ntiles)
{
    __shared__ union {
        unsigned short Qs[QB * D];                                   // 64 KB
        struct { float ms[QB][16][MPCL]; int mi[QB][16][MPCL]; } mg; // 24 KB
    } u;

    const int tid = threadIdx.x;
    const int wave = tid >> 6;
    const int lane = tid & 63;
    const int quad = lane >> 4;
    const int l15 = lane & 15;
    const int qt = blockIdx.x;
    const int chunk = blockIdx.y;

    // ---- stage Q once, k-segment XOR-swizzled by row (conflict-free reads) ----
    {
        const unsigned short* qg = Qbf + (size_t)qt * QB * D;
#pragma unroll
        for (int i = 0; i < 16; ++i) {
            int flat = i * 256 + tid;     // 0..4095 segments of 8 elems
            int r = flat >> 6;
            int s = flat & 63;
            uint4 v = *(const uint4*)(qg + (size_t)r * D + s * 8);
            *(uint4*)&u.Qs[r * D + (s ^ (r & 7)) * 8] = v;
        }
    }
    __syncthreads();

    float ls[4][MPCL]; int li[4][MPCL];
#pragma unroll
    for (int tj = 0; tj < 4; ++tj)
#pragma unroll
        for (int r = 0; r < MPCL; ++r) { ls[tj][r] = FLT_MAX; li[tj][r] = -1; }

    for (int tile = chunk; tile < ntiles; tile += NCH) {
        const int pb = tile * PB + wave * PW;   // this wave's 64 points
        const unsigned short* xp = Xbf + (size_t)(pb + l15) * D + quad * 8;

        f32x4 acc[4][4];
#pragma unroll
        for (int ti = 0; ti < 4; ++ti)
#pragma unroll
            for (int tj = 0; tj < 4; ++tj) acc[ti][tj] = (f32x4){0.f, 0.f, 0.f, 0.f};

        // 2-deep X-fragment pipeline: x0 holds even k0, x1 odd k0
        short8 x0[4], x1[4];
#pragma unroll
        for (int ti = 0; ti < 4; ++ti) x0[ti] = *(const short8*)(xp + ti * 16 * D);
#pragma unroll
        for (int ti = 0; ti < 4; ++ti) x1[ti] = *(const short8*)(xp + ti * 16 * D + 32);

#pragma unroll
        for (int kk = 0; kk < 8; ++kk) {
            // even k0 = 2kk
#pragma unroll
            for (int tj = 0; tj < 4; ++tj) {
                int r = tj * 16 + l15;
                int seg = ((2 * kk) * 4 + quad) ^ (r & 7);
                short8 qf = *(const short8*)&u.Qs[r * D + seg * 8];
#pragma unroll
                for (int ti = 0; ti < 4; ++ti)
                    acc[ti][tj] = __builtin_amdgcn_mfma_f32_16x16x32_bf16(
                        x0[ti], qf, acc[ti][tj], 0, 0, 0);
            }
            if (kk < 7) {
#pragma unroll
                for (int ti = 0; ti < 4; ++ti)
                    x0[ti] = *(const short8*)(xp + ti * 16 * D + (2 * kk + 2) * 32);
            }
            // odd k0 = 2kk+1
#pragma unroll
            for (int tj = 0; tj < 4; ++tj) {
                int r = tj * 16 + l15;
                int seg = ((2 * kk + 1) * 4 + quad) ^ (r & 7);
                short8 qf = *(const short8*)&u.Qs[r * D + seg * 8];
#pragma unroll
                for (int ti = 0; ti < 4; ++ti)
                    acc[ti][tj] = __builtin_amdgcn_mfma_f32_16x16x32_bf16(
                        x1[ti], qf, acc[ti][tj], 0, 0, 0);
            }
            if (kk < 7) {
#pragma unroll
                for (int ti = 0; ti < 4; ++ti)
                    x1[ti] = *(const short8*)(xp + ti * 16 * D + (2 * kk + 3) * 32);
            }
        }

        // selection: acc row (quad*4+reg, + ti*16) = point, col l15 (+tj*16) = query
#pragma unroll
        for (int ti = 0; ti < 4; ++ti) {
            float4 xs = *(const float4*)&xsq[pb + ti * 16 + quad * 4];
            float xsv[4] = {xs.x, xs.y, xs.z, xs.w};
#pragma unroll
            for (int tj = 0; tj < 4; ++tj)
#pragma unroll
                for (int rg = 0; rg < 4; ++rg)
                    insertK<MPCL>(ls[tj], li[tj], acc[ti][tj][rg] + xsv[rg],
                                  pb + ti * 16 + quad * 4 + rg);
        }
    }

    // ---- block-level merge: 16 cell-lists per query -> top-8 per (query,chunk) ----
    __syncthreads();   // Q no longer needed; reuse LDS
#pragma unroll
    for (int tj = 0; tj < 4; ++tj)
#pragma unroll
        for (int r = 0; r < MPCL; ++r) {
            u.mg.ms[tj * 16 + l15][wave * 4 + quad][r] = ls[tj][r];
            u.mg.mi[tj * 16 + l15][wave * 4 + quad][r] = li[tj][r];
        }
    __syncthreads();
    if (tid < QB) {
        float fs[MPC]; int fi[MPC];
#pragma unroll
        for (int r = 0; r < MPC; ++r) { fs[r] = FLT_MAX; fi[r] = -1; }
        for (int s = 0; s < 16; ++s)
#pragma unroll
            for (int r = 0; r < MPCL; ++r)
                insertK<MPC>(fs, fi, u.mg.ms[tid][s][r], u.mg.mi[tid][s][r]);
        size_t base = ((size_t)(qt * QB + tid) * NCH + chunk) * MPC;
#pragma unroll
        for (int r = 0; r < MPC; ++r) { candS[base + r] = fs[r]; candI[base + r] = fi[r]; }
    }
}

// Per query: wave-parallel merge of 64 sorted chunk-lists -> approx top-16 ->
// exact fp32 rescore -> exact top-5 -> gather + mean.
__global__ void rescore_kernel(const float* __restrict__ Q, const float* __restrict__ X,
                               const float* __restrict__ xsq,
                               const float* __restrict__ candS, const int* __restrict__ candI,
                               float* __restrict__ out) {
    const int b = blockIdx.x;
    const int tid = threadIdx.x;
    const int wave = tid >> 6;
    const int lane = tid & 63;
    __shared__ int exI[TR];
    __shared__ float exS[TR];
    __shared__ int top5[5];

    if (wave == 0) {
        const float* cs = candS + (size_t)b * NCH * MPC;
        const int* ci = candI + (size_t)b * NCH * MPC;
        int h = 0;
        float cur = cs[lane * MPC];
        for (int r = 0; r < TR; ++r) {
            float v = cur; int wl = lane;
#pragma unroll
            for (int off = 1; off < 64; off <<= 1) {
                float ov = __shfl_xor(v, off, 64);
                int owl = __shfl_xor(wl, off, 64);
                if (ov < v || (ov == v && owl < wl)) { v = ov; wl = owl; }
            }
            if (lane == wl) {
                exI[r] = ci[lane * MPC + h];
                ++h;
                cur = (h < MPC) ? cs[lane * MPC + h] : FLT_MAX;
            }
        }
    }
    __syncthreads();

    const float* qr = Q + (size_t)b * D;
#pragma unroll
    for (int cc = 0; cc < 4; ++cc) {
        int c = wave * 4 + cc;
        int idx = exI[c];
        const float* xr = X + (size_t)idx * D;
        float4 qa = *(const float4*)(qr + lane * 8);
        float4 qb = *(const float4*)(qr + lane * 8 + 4);
        float4 xa = *(const float4*)(xr + lane * 8);
        float4 xb = *(const float4*)(xr + lane * 8 + 4);
        float p = qa.x * xa.x + qa.y * xa.y + qa.z * xa.z + qa.w * xa.w
                + qb.x * xb.x + qb.y * xb.y + qb.z * xb.z + qb.w * xb.w;
#pragma unroll
        for (int off = 32; off > 0; off >>= 1) p += __shfl_down(p, off, 64);
        if (lane == 0) exS[c] = xsq[idx] - 2.0f * p;
    }
    __syncthreads();

    if (tid == 0) {
        float fs[5]; int fi[5];
#pragma unroll
        for (int r = 0; r < 5; ++r) { fs[r] = FLT_MAX; fi[r] = -1; }
        for (int i = 0; i < TR; ++i) insertK<5>(fs, fi, exS[i], exI[i]);
#pragma unroll
        for (int r = 0; r < 5; ++r) top5[r] = fi[r];
    }
    __syncthreads();

#pragma unroll
    for (int dd = 0; dd < 2; ++dd) {
        int d = tid + dd * 256;
        float s = 0.0f;
#pragma unroll
        for (int r = 0; r < 5; ++r) s += X[(size_t)top5[r] * D + d];
        out[(size_t)b * D + d] = s / 5.0f;
    }
}

extern "C" void kernel_launch(void* const* d_in, const int* in_sizes, int n_in,
                              void* d_out, int out_size, void* d_ws, size_t ws_size,
                              hipStream_t stream) {
    const float* x_enc = (const float*)d_in[0];
    const float* X_fit = (const float*)d_in[1];
    float* out = (float*)d_out;
    const int B = in_sizes[0] / D;               // 2048
    const int N = in_sizes[1] / D;               // 100000
    const int padN = ((N + PB - 1) / PB) * PB;   // 100096
    const int ntiles = padN / PB;                // 391
    const int qblocks = B / QB;                  // 32

    char* w = (char*)d_ws;
    unsigned short* Xbf = (unsigned short*)w;            w += (size_t)padN * D * 2;
    unsigned short* Qbf = (unsigned short*)w;            w += (size_t)B * D * 2;
    float* xsq = (float*)w;                              w += (size_t)padN * 4;
    float* candS = (float*)w;                            w += (size_t)B * NCH * MPC * 4;
    int* candI = (int*)w;

    hipLaunchKernelGGL(convert_x, dim3(padN / 4), dim3(256), 0, stream, X_fit, Xbf, xsq, N, padN);
    hipLaunchKernelGGL(convert_q, dim3(B / 4), dim3(256), 0, stream, x_enc, Qbf);
    hipLaunchKernelGGL(score_mfma, dim3(qblocks, NCH), dim3(256), 0, stream,
                       Qbf, Xbf, xsq, candS, candI, ntiles);
    hipLaunchKernelGGL(rescore_kernel, dim3(B), dim3(256), 0, stream,
                       x_enc, X_fit, xsq, candS, candI, out);
}